// Round 4
// baseline (296.485 us; speedup 1.0000x reference)
//
#include <hip/hip_runtime.h>

#define TT 7
#define DD 40
#define HH 64
#define RB 16          // rows per block
#define NTH 256        // 4 waves (one per j-quarter)
#define HS 72          // u16 row stride (144 B -> 2-way-free b128 reads)
#define PL (RB*HS)     // 1152 u16 per plane (2304 B)

typedef _Float16 f16x8 __attribute__((ext_vector_type(8)));
typedef float f32x4 __attribute__((ext_vector_type(4)));

#define MFMA(acc, a, b) acc = __builtin_amdgcn_mfma_f32_16x16x32_f16(a, b, acc, 0, 0, 0)

__device__ __forceinline__ float fast_rcp(float x) { return __builtin_amdgcn_rcpf(x); }
__device__ __forceinline__ float sigf(float x)   { return fast_rcp(1.f + __expf(-x)); }
__device__ __forceinline__ float tanhf_(float x) { return 1.f - 2.f * fast_rcp(1.f + __expf(2.f * x)); }
__device__ __forceinline__ unsigned short u16c(_Float16 h) { return __builtin_bit_cast(unsigned short, h); }

__device__ __forceinline__ f16x8 zf() {
  f16x8 r;
  #pragma unroll
  for (int i = 0; i < 8; ++i) r[i] = (_Float16)0.f;
  return r;
}
__device__ __forceinline__ f16x8 cvt8(const float* p) {
  float4 a = *(const float4*)p, b = *(const float4*)(p + 4);
  f16x8 r;
  r[0] = (_Float16)a.x; r[1] = (_Float16)a.y; r[2] = (_Float16)a.z; r[3] = (_Float16)a.w;
  r[4] = (_Float16)b.x; r[5] = (_Float16)b.y; r[6] = (_Float16)b.z; r[7] = (_Float16)b.w;
  return r;
}
__device__ __forceinline__ void split8v(float4 a, float4 b, f16x8 &hi, f16x8 &lo) {
  float t0[8] = {a.x, a.y, a.z, a.w, b.x, b.y, b.z, b.w};
  #pragma unroll
  for (int i = 0; i < 8; ++i) {
    _Float16 h = (_Float16)t0[i];
    hi[i] = h;
    lo[i] = (_Float16)(t0[i] - (float)h);
  }
}

__global__ __launch_bounds__(NTH, 5) void lstm2_mfma5_kernel(
    const float* __restrict__ x,
    const float* __restrict__ Wih0, const float* __restrict__ Whh0,
    const float* __restrict__ bih0, const float* __restrict__ bhh0,
    const float* __restrict__ Wih1, const float* __restrict__ Whh1,
    const float* __restrict__ bih1, const float* __restrict__ bhh1,
    const float* __restrict__ W1, const float* __restrict__ b1,
    const float* __restrict__ W2, const float* __restrict__ b2,
    float* __restrict__ out)
{
  // 25,344 B total -> 5 blocks/CU with launch_bounds(256,5)
  __shared__ __align__(16) unsigned short s_hist[TT * PL];  // layer-0 h (hi), all t
  __shared__ __align__(16) unsigned short s_lo[2 * PL];     // h (lo) ping-pong, shared by both layers
  __shared__ __align__(16) unsigned short s_h2[2 * PL];     // layer-1 h (hi) ping-pong

  const int tid = threadIdx.x;
  const int l   = tid & 63;
  const int wn  = tid >> 6;        // j-quarter 0..3
  const int l15 = l & 15;
  const int lg  = l >> 4;          // k-group (A/B), C row subgroup
  const int jj  = wn * 16 + l15;   // hidden col owned by this lane
  const int blk = blockIdx.x;
  const int k0l = lg * 8;

  f16x8 Bx[4][2], Bh[4][2];
  float bias[4], cst[4];

  #pragma unroll 1
  for (int layer = 0; layer < 2; ++layer) {
    const float* Wi  = layer ? Wih1 : Wih0;
    const float* Wh  = layer ? Whh1 : Whh0;
    const float* bi  = layer ? bih1 : bih0;
    const float* bh_ = layer ? bhh1 : bhh0;
    const int Kin = layer ? HH : DD;

    #pragma unroll
    for (int g = 0; g < 4; ++g) {
      int n = g * 64 + jj;
      #pragma unroll
      for (int kt = 0; kt < 2; ++kt) {
        int k0 = kt * 32 + k0l;
        Bx[g][kt] = (k0 + 8 <= Kin) ? cvt8(&Wi[n * Kin + k0]) : zf();
        Bh[g][kt] = cvt8(&Wh[n * HH + k0]);
      }
      bias[g] = bi[n] + bh_[n];
      cst[g] = 0.f;
    }

    #pragma unroll 1
    for (int t = 0; t < TT; ++t) {
      if (layer + t) __syncthreads();

      if (layer == 1 && t == 5) {   // stage FC weights into consumed hist planes 0..3
        float* wst = (float*)s_hist;
        for (int i = tid; i < 2113; i += NTH) {
          float v;
          if (i < 2048)      v = W1[i];
          else if (i < 2080) v = b1[i - 2048];
          else if (i < 2112) v = W2[i - 2080];
          else               v = b2[0];
          wst[i] = v;
        }
      }

      f32x4 acc[4];
      #pragma unroll
      for (int g = 0; g < 4; ++g) acc[g] = (f32x4){bias[g], bias[g], bias[g], bias[g]};

      // ---- input contribution ----
      if (layer == 0) {
        const float* px = x + (blk * RB + l15) * (TT * DD) + t * DD;
        f16x8 xh0, xl0, xh1, xl1;
        {
          float4 xa = *(const float4*)&px[k0l];
          float4 xb = *(const float4*)&px[k0l + 4];     // k0l+8 <= 32 <= DD
          split8v(xa, xb, xh0, xl0);
        }
        if (lg == 0) {                                   // kt1 valid only for lg==0 (k=32..39)
          float4 xc = *(const float4*)&px[32];
          float4 xd = *(const float4*)&px[36];
          split8v(xc, xd, xh1, xl1);
        } else { xh1 = zf(); xl1 = zf(); }
        __builtin_amdgcn_s_setprio(1);
        #pragma unroll
        for (int g = 0; g < 4; ++g) MFMA(acc[g], xh0, Bx[g][0]);
        #pragma unroll
        for (int g = 0; g < 4; ++g) MFMA(acc[g], xl0, Bx[g][0]);
        #pragma unroll
        for (int g = 0; g < 4; ++g) MFMA(acc[g], xh1, Bx[g][1]);
        #pragma unroll
        for (int g = 0; g < 4; ++g) MFMA(acc[g], xl1, Bx[g][1]);
        __builtin_amdgcn_s_setprio(0);
      } else {
        const unsigned short* ip = s_hist + t * PL + l15 * HS;
        f16x8 ih0 = *(const f16x8*)(ip + k0l);
        f16x8 ih1 = *(const f16x8*)(ip + 32 + k0l);
        __builtin_amdgcn_s_setprio(1);
        #pragma unroll
        for (int g = 0; g < 4; ++g) MFMA(acc[g], ih0, Bx[g][0]);
        #pragma unroll
        for (int g = 0; g < 4; ++g) MFMA(acc[g], ih1, Bx[g][1]);
        __builtin_amdgcn_s_setprio(0);
      }

      // ---- recurrent contribution (hi + lo) ----
      if (t > 0) {
        const unsigned short* hp =
            (layer ? s_h2 + ((t - 1) & 1) * PL : s_hist + (t - 1) * PL) + l15 * HS;
        const unsigned short* lp = s_lo + ((t - 1) & 1) * PL + l15 * HS;
        f16x8 rh0 = *(const f16x8*)(hp + k0l);
        f16x8 rh1 = *(const f16x8*)(hp + 32 + k0l);
        f16x8 rl0 = *(const f16x8*)(lp + k0l);
        f16x8 rl1 = *(const f16x8*)(lp + 32 + k0l);
        __builtin_amdgcn_s_setprio(1);
        #pragma unroll
        for (int g = 0; g < 4; ++g) MFMA(acc[g], rh0, Bh[g][0]);
        #pragma unroll
        for (int g = 0; g < 4; ++g) MFMA(acc[g], rh1, Bh[g][1]);
        #pragma unroll
        for (int g = 0; g < 4; ++g) MFMA(acc[g], rl0, Bh[g][0]);
        #pragma unroll
        for (int g = 0; g < 4; ++g) MFMA(acc[g], rl1, Bh[g][1]);
        __builtin_amdgcn_s_setprio(0);
      }

      // ---- epilogue ----
      #pragma unroll
      for (int r = 0; r < 4; ++r) {
        float ig = sigf(acc[0][r]);
        float fg = sigf(acc[1][r]);
        float gg = tanhf_(acc[2][r]);
        float og = sigf(acc[3][r]);
        float c  = fg * cst[r] + ig * gg;
        cst[r] = c;
        float h  = og * tanhf_(c);
        int row = lg * 4 + r;
        _Float16 hh = (_Float16)h;
        _Float16 hl = (_Float16)(h - (float)hh);
        if (layer == 0) {
          s_hist[t * PL + row * HS + jj]     = u16c(hh);
          s_lo[(t & 1) * PL + row * HS + jj] = u16c(hl);
        } else if (t < TT - 1) {
          s_h2[(t & 1) * PL + row * HS + jj] = u16c(hh);
          s_lo[(t & 1) * PL + row * HS + jj] = u16c(hl);
        } else {
          ((float*)(s_hist + 4 * PL))[row * 68 + jj] = h;  // final h2 f32 (planes 4-5)
        }
      }
    }
  }

  // ---- FC head ----
  __syncthreads();
  {
    const float* wfc = (const float*)s_hist;             // W1|b1|W2|b2 (planes 0-3)
    const float* h2f = (const float*)(s_hist + 4 * PL);  // [16][68] f32
    float* hid = (float*)s_h2;                           // [16][36] f32 scratch
    int row = tid >> 4;
    int f0  = (tid & 15) * 2;
    int rot = (tid & 15) * 4;                            // de-conflict W1 reads
    float a0 = wfc[2048 + f0], a1 = wfc[2048 + f0 + 1];
    #pragma unroll
    for (int k8 = 0; k8 < HH; k8 += 4) {
      int kk = (k8 + rot) & 63;
      float4 hv = *(const float4*)&h2f[row * 68 + kk];
      float4 w0 = *(const float4*)&wfc[(f0    ) * HH + kk];
      float4 w1 = *(const float4*)&wfc[(f0 + 1) * HH + kk];
      a0 += hv.x * w0.x + hv.y * w0.y + hv.z * w0.z + hv.w * w0.w;
      a1 += hv.x * w1.x + hv.y * w1.y + hv.z * w1.z + hv.w * w1.w;
    }
    hid[row * 36 + f0]     = fmaxf(a0, 0.f);
    hid[row * 36 + f0 + 1] = fmaxf(a1, 0.f);
  }
  __syncthreads();
  if (tid < RB) {
    const float* wfc = (const float*)s_hist;
    const float* hid = (const float*)s_h2;
    float a = wfc[2112];
    #pragma unroll
    for (int kk = 0; kk < 32; ++kk) a += hid[tid * 36 + kk] * wfc[2080 + kk];
    out[blk * RB + tid] = a;
  }
}

extern "C" void kernel_launch(void* const* d_in, const int* in_sizes, int n_in,
                              void* d_out, int out_size, void* d_ws, size_t ws_size,
                              hipStream_t stream) {
  const float* x    = (const float*)d_in[0];
  const float* Wih0 = (const float*)d_in[1];
  const float* Whh0 = (const float*)d_in[2];
  const float* bih0 = (const float*)d_in[3];
  const float* bhh0 = (const float*)d_in[4];
  const float* Wih1 = (const float*)d_in[5];
  const float* Whh1 = (const float*)d_in[6];
  const float* bih1 = (const float*)d_in[7];
  const float* bhh1 = (const float*)d_in[8];
  const float* W1   = (const float*)d_in[9];
  const float* b1   = (const float*)d_in[10];
  const float* W2   = (const float*)d_in[11];
  const float* b2   = (const float*)d_in[12];
  float* out = (float*)d_out;

  const int Btot = in_sizes[0] / (TT * DD);   // 32768
  dim3 grid(Btot / RB), block(NTH);
  lstm2_mfma5_kernel<<<grid, block, 0, stream>>>(
      x, Wih0, Whh0, bih0, bhh0, Wih1, Whh1, bih1, bhh1, W1, b1, W2, b2, out);
}

// Round 5
// 119.747 us; speedup vs baseline: 2.4759x; 2.4759x over previous
//
#include <hip/hip_runtime.h>

#define TT 7
#define DD 40
#define HH 64
#define RB 16          // rows per block
#define NTH 256        // 4 waves (one per j-quarter)
#define HS 72          // u16 stride within h planes (144 B rows)
#define PL (RB*HS)     // 1152 u16 per plane

typedef _Float16 f16x8 __attribute__((ext_vector_type(8)));
typedef float f32x4 __attribute__((ext_vector_type(4)));

#define MFMA(acc, a, b) acc = __builtin_amdgcn_mfma_f32_16x16x32_f16(a, b, acc, 0, 0, 0)

__device__ __forceinline__ float fast_rcp(float x) { return __builtin_amdgcn_rcpf(x); }
__device__ __forceinline__ float sigf(float x)   { return fast_rcp(1.f + __expf(-x)); }
__device__ __forceinline__ float tanhf_(float x) { return 1.f - 2.f * fast_rcp(1.f + __expf(2.f * x)); }
__device__ __forceinline__ unsigned short u16c(_Float16 h) { return __builtin_bit_cast(unsigned short, h); }

__device__ __forceinline__ f16x8 zf() {
  f16x8 r;
  #pragma unroll
  for (int i = 0; i < 8; ++i) r[i] = (_Float16)0.f;
  return r;
}
__device__ __forceinline__ f16x8 cvt8(const float* p) {
  float4 a = *(const float4*)p, b = *(const float4*)(p + 4);
  f16x8 r;
  r[0] = (_Float16)a.x; r[1] = (_Float16)a.y; r[2] = (_Float16)a.z; r[3] = (_Float16)a.w;
  r[4] = (_Float16)b.x; r[5] = (_Float16)b.y; r[6] = (_Float16)b.z; r[7] = (_Float16)b.w;
  return r;
}
__device__ __forceinline__ void split8v(float4 a, float4 b, f16x8 &hi, f16x8 &lo) {
  float t0[8] = {a.x, a.y, a.z, a.w, b.x, b.y, b.z, b.w};
  #pragma unroll
  for (int i = 0; i < 8; ++i) {
    _Float16 h = (_Float16)t0[i];
    hi[i] = h;
    lo[i] = (_Float16)(t0[i] - (float)h);
  }
}

__global__ __launch_bounds__(NTH, 2) void lstm2_fusedpipe_kernel(
    const float* __restrict__ x,
    const float* __restrict__ Wih0, const float* __restrict__ Whh0,
    const float* __restrict__ bih0, const float* __restrict__ bhh0,
    const float* __restrict__ Wih1, const float* __restrict__ Whh1,
    const float* __restrict__ bih1, const float* __restrict__ bhh1,
    const float* __restrict__ W1, const float* __restrict__ b1,
    const float* __restrict__ W2, const float* __restrict__ b2,
    float* __restrict__ out)
{
  // 8 h-planes, 18432 B total:
  // [0..1]: h1 hi ping-pong  [2..3]: h1 lo ping-pong
  // [4..5]: h2 hi ping-pong  [6..7]: h2 lo ping-pong
  __shared__ __align__(16) unsigned short s_mem[8 * PL];

  const int tid = threadIdx.x;
  const int l   = tid & 63;
  const int wn  = tid >> 6;        // j-quarter 0..3
  const int l15 = l & 15;
  const int lg  = l >> 4;          // k-group (A/B); C row subgroup
  const int jj  = wn * 16 + l15;
  const int blk = blockIdx.x;
  const int k0l = lg * 8;
  const int rdoff = l15 * HS + k0l;       // A-frag read offset within a plane
  const int wroff = (lg * 4) * HS + jj;   // C write offset within a plane

  // ---- x[0] prefetch (earliest possible issue) ----
  const float* px = x + (blk * RB + l15) * (TT * DD);
  float4 xa = *(const float4*)&px[k0l];
  float4 xb = *(const float4*)&px[k0l + 4];
  float4 xc = *(const float4*)&px[32];
  float4 xd = *(const float4*)&px[36];

  // ---- weight fragments (all registers, single f16) ----
  f16x8 Bh0[4][2], Bh1[4][2], Bx1[4][2], Bx0k0[4], Bx0m[4];
  float bias1v[4], cst0[4], cst1[4];
  #pragma unroll
  for (int g = 0; g < 4; ++g) {
    int n = g * 64 + jj;
    #pragma unroll
    for (int kt = 0; kt < 2; ++kt) {
      Bh0[g][kt] = cvt8(&Whh0[n * HH + kt * 32 + k0l]);
      Bh1[g][kt] = cvt8(&Whh1[n * HH + kt * 32 + k0l]);
      Bx1[g][kt] = cvt8(&Wih1[n * HH + kt * 32 + k0l]);
    }
    Bx0k0[g] = cvt8(&Wih0[n * DD + k0l]);         // k = lg*8 .. +8 (0..31)
    // merged tile: lg0 = Wih0[n][32..39] (for x_hi), lg1 = same (for x_lo),
    // lg2 slot0 = bias0[n] (A carries 1.0), lg3 = 0
    f16x8 f = zf();
    if (lg <= 1)      f = cvt8(&Wih0[n * DD + 32]);
    else if (lg == 2) f[0] = (_Float16)(bih0[n] + bhh0[n]);
    Bx0m[g] = f;
    bias1v[g] = bih1[n] + bhh1[n];
    cst0[g] = 0.f; cst1[g] = 0.f;
  }

  #pragma unroll 1
  for (int s = 0; s < TT; ++s) {
    if (s) __syncthreads();

    // ---- h1[s-1] fragments (shared by L0-recurrent and L1-input) ----
    f16x8 h1h0 = zf(), h1h1 = zf(), h1l0 = zf(), h1l1 = zf();
    if (s >= 1) {
      const unsigned short* ph = s_mem + ((s - 1) & 1) * PL + rdoff;
      h1h0 = *(const f16x8*)ph;
      h1h1 = *(const f16x8*)(ph + 32);
      const unsigned short* pl_ = s_mem + (2 + ((s - 1) & 1)) * PL + rdoff;
      h1l0 = *(const f16x8*)pl_;
      h1l1 = *(const f16x8*)(pl_ + 32);
    }

    // ---- L0: compute h1[s] ----
    f32x4 acc0[4];
    #pragma unroll
    for (int g = 0; g < 4; ++g) acc0[g] = (f32x4){0.f, 0.f, 0.f, 0.f};
    f16x8 xh0, xl0, ch, cl;
    split8v(xa, xb, xh0, xl0);
    split8v(xc, xd, ch, cl);
    f16x8 am1 = (lg == 0) ? ch : ((lg == 1) ? cl : zf());
    if (lg == 2) am1[0] = (_Float16)1.f;

    __builtin_amdgcn_s_setprio(1);
    #pragma unroll
    for (int g = 0; g < 4; ++g) MFMA(acc0[g], xh0, Bx0k0[g]);
    #pragma unroll
    for (int g = 0; g < 4; ++g) MFMA(acc0[g], xl0, Bx0k0[g]);
    #pragma unroll
    for (int g = 0; g < 4; ++g) MFMA(acc0[g], am1, Bx0m[g]);   // + bias0 via 1.0 slot
    if (s >= 1) {
      #pragma unroll
      for (int g = 0; g < 4; ++g) MFMA(acc0[g], h1h0, Bh0[g][0]);
      #pragma unroll
      for (int g = 0; g < 4; ++g) MFMA(acc0[g], h1h1, Bh0[g][1]);
      #pragma unroll
      for (int g = 0; g < 4; ++g) MFMA(acc0[g], h1l0, Bh0[g][0]);
      #pragma unroll
      for (int g = 0; g < 4; ++g) MFMA(acc0[g], h1l1, Bh0[g][1]);
    }
    __builtin_amdgcn_s_setprio(0);

    // ---- prefetch x[s+1] (hides HBM latency under L1 + epilogues + barrier) ----
    if (s < TT - 1) {
      const float* pn = px + (s + 1) * DD;
      xa = *(const float4*)&pn[k0l];
      xb = *(const float4*)&pn[k0l + 4];
      xc = *(const float4*)&pn[32];
      xd = *(const float4*)&pn[36];
    }

    // ---- L0 epilogue -> h1[s] planes ----
    {
      const int hb = ((s & 1)) * PL + wroff;
      const int lb = (2 + (s & 1)) * PL + wroff;
      #pragma unroll
      for (int r = 0; r < 4; ++r) {
        float ig = sigf(acc0[0][r]);
        float fg = sigf(acc0[1][r]);
        float gg = tanhf_(acc0[2][r]);
        float og = sigf(acc0[3][r]);
        float c  = fg * cst0[r] + ig * gg;
        cst0[r] = c;
        float h  = og * tanhf_(c);
        _Float16 hh = (_Float16)h;
        s_mem[hb + r * HS] = u16c(hh);
        s_mem[lb + r * HS] = u16c((_Float16)(h - (float)hh));
      }
    }

    // ---- L1: compute h2[s-1] ----
    if (s >= 1) {
      f32x4 acc1[4];
      #pragma unroll
      for (int g = 0; g < 4; ++g)
        acc1[g] = (f32x4){bias1v[g], bias1v[g], bias1v[g], bias1v[g]};

      __builtin_amdgcn_s_setprio(1);
      #pragma unroll
      for (int g = 0; g < 4; ++g) MFMA(acc1[g], h1h0, Bx1[g][0]);
      #pragma unroll
      for (int g = 0; g < 4; ++g) MFMA(acc1[g], h1h1, Bx1[g][1]);
      if (s >= 2) {
        // h2[s-2] fragments (hi plane 4+(s&1), lo plane 6+(s&1))
        const unsigned short* p2h = s_mem + (4 + (s & 1)) * PL + rdoff;
        f16x8 r2h0 = *(const f16x8*)p2h;
        f16x8 r2h1 = *(const f16x8*)(p2h + 32);
        const unsigned short* p2l = s_mem + (6 + (s & 1)) * PL + rdoff;
        f16x8 r2l0 = *(const f16x8*)p2l;
        f16x8 r2l1 = *(const f16x8*)(p2l + 32);
        #pragma unroll
        for (int g = 0; g < 4; ++g) MFMA(acc1[g], r2h0, Bh1[g][0]);
        #pragma unroll
        for (int g = 0; g < 4; ++g) MFMA(acc1[g], r2h1, Bh1[g][1]);
        #pragma unroll
        for (int g = 0; g < 4; ++g) MFMA(acc1[g], r2l0, Bh1[g][0]);
        #pragma unroll
        for (int g = 0; g < 4; ++g) MFMA(acc1[g], r2l1, Bh1[g][1]);
      }
      __builtin_amdgcn_s_setprio(0);

      // epilogue -> h2[s-1] planes (hi 4+((s-1)&1), lo 6+((s-1)&1))
      const int hb = (4 + ((s - 1) & 1)) * PL + wroff;
      const int lb = (6 + ((s - 1) & 1)) * PL + wroff;
      #pragma unroll
      for (int r = 0; r < 4; ++r) {
        float ig = sigf(acc1[0][r]);
        float fg = sigf(acc1[1][r]);
        float gg = tanhf_(acc1[2][r]);
        float og = sigf(acc1[3][r]);
        float c  = fg * cst1[r] + ig * gg;
        cst1[r] = c;
        float h  = og * tanhf_(c);
        _Float16 hh = (_Float16)h;
        s_mem[hb + r * HS] = u16c(hh);
        s_mem[lb + r * HS] = u16c((_Float16)(h - (float)hh));
      }
    }
  }

  // ---- final step: L1 computes h2[6] ----
  __syncthreads();
  {
    // h1[6] hi: plane (6&1)=0 ; h2[5]: hi plane 4+(5&1)=5, lo plane 6+1=7
    const unsigned short* ph = s_mem + 0 * PL + rdoff;
    f16x8 ih0 = *(const f16x8*)ph;
    f16x8 ih1 = *(const f16x8*)(ph + 32);
    const unsigned short* p2h = s_mem + 5 * PL + rdoff;
    f16x8 r2h0 = *(const f16x8*)p2h;
    f16x8 r2h1 = *(const f16x8*)(p2h + 32);
    const unsigned short* p2l = s_mem + 7 * PL + rdoff;
    f16x8 r2l0 = *(const f16x8*)p2l;
    f16x8 r2l1 = *(const f16x8*)(p2l + 32);

    f32x4 acc1[4];
    #pragma unroll
    for (int g = 0; g < 4; ++g)
      acc1[g] = (f32x4){bias1v[g], bias1v[g], bias1v[g], bias1v[g]};
    __builtin_amdgcn_s_setprio(1);
    #pragma unroll
    for (int g = 0; g < 4; ++g) MFMA(acc1[g], ih0, Bx1[g][0]);
    #pragma unroll
    for (int g = 0; g < 4; ++g) MFMA(acc1[g], ih1, Bx1[g][1]);
    #pragma unroll
    for (int g = 0; g < 4; ++g) MFMA(acc1[g], r2h0, Bh1[g][0]);
    #pragma unroll
    for (int g = 0; g < 4; ++g) MFMA(acc1[g], r2h1, Bh1[g][1]);
    #pragma unroll
    for (int g = 0; g < 4; ++g) MFMA(acc1[g], r2l0, Bh1[g][0]);
    #pragma unroll
    for (int g = 0; g < 4; ++g) MFMA(acc1[g], r2l1, Bh1[g][1]);
    __builtin_amdgcn_s_setprio(0);

    // write final h2 as f32 into planes 2-3 region ([16][72] f32, free at this point)
    float* h2f = (float*)(s_mem + 2 * PL);
    #pragma unroll
    for (int r = 0; r < 4; ++r) {
      float ig = sigf(acc1[0][r]);
      float fg = sigf(acc1[1][r]);
      float gg = tanhf_(acc1[2][r]);
      float og = sigf(acc1[3][r]);
      float c  = fg * cst1[r] + ig * gg;
      float h  = og * tanhf_(c);
      h2f[(lg * 4 + r) * HS + jj] = h;
    }
  }
  __syncthreads();

  // ---- FC head (weights straight from global/L2) ----
  {
    const float* h2f = (const float*)(s_mem + 2 * PL);   // [16][72] f32
    float* hid = (float*)s_mem;                          // [16][36] f32 (planes 0-1, dead)
    #pragma unroll 1
    for (int p = tid; p < 512; p += NTH) {
      int row = p >> 5, fc = p & 31;
      float a = b1[fc];
      #pragma unroll
      for (int k = 0; k < HH; k += 4) {
        float4 hv = *(const float4*)&h2f[row * HS + k];
        float4 wv = *(const float4*)&W1[fc * HH + k];
        a += hv.x * wv.x + hv.y * wv.y + hv.z * wv.z + hv.w * wv.w;
      }
      hid[row * 36 + fc] = fmaxf(a, 0.f);
    }
  }
  __syncthreads();
  if (tid < RB) {
    const float* hid = (const float*)s_mem;
    float a = b2[0];
    #pragma unroll
    for (int k = 0; k < 32; ++k) a += hid[tid * 36 + k] * W2[k];
    out[blk * RB + tid] = a;
  }
}

extern "C" void kernel_launch(void* const* d_in, const int* in_sizes, int n_in,
                              void* d_out, int out_size, void* d_ws, size_t ws_size,
                              hipStream_t stream) {
  const float* x    = (const float*)d_in[0];
  const float* Wih0 = (const float*)d_in[1];
  const float* Whh0 = (const float*)d_in[2];
  const float* bih0 = (const float*)d_in[3];
  const float* bhh0 = (const float*)d_in[4];
  const float* Wih1 = (const float*)d_in[5];
  const float* Whh1 = (const float*)d_in[6];
  const float* bih1 = (const float*)d_in[7];
  const float* bhh1 = (const float*)d_in[8];
  const float* W1   = (const float*)d_in[9];
  const float* b1   = (const float*)d_in[10];
  const float* W2   = (const float*)d_in[11];
  const float* b2   = (const float*)d_in[12];
  float* out = (float*)d_out;

  const int Btot = in_sizes[0] / (TT * DD);   // 32768
  dim3 grid(Btot / RB), block(NTH);
  lstm2_fusedpipe_kernel<<<grid, block, 0, stream>>>(
      x, Wih0, Whh0, bih0, bhh0, Wih1, Whh1, bih1, bhh1, W1, b1, W2, b2, out);
}

// Round 6
// 76.668 us; speedup vs baseline: 3.8671x; 1.5619x over previous
//
#include <hip/hip_runtime.h>

#define TT 7
#define DD 40
#define HH 64
#define RB 64          // rows per block
#define NRT 4          // row-tiles of 16
#define NTH 256        // 4 waves, one j-quarter each
#define HS 72          // u16 stride in h planes (144 B rows -> conflict-free b128)
#define XP 44          // float stride of x rows in LDS (11 x 16B chunks)

typedef _Float16 f16x8 __attribute__((ext_vector_type(8)));
typedef float f32x4 __attribute__((ext_vector_type(4)));

#define MFMA(acc, a, b) acc = __builtin_amdgcn_mfma_f32_16x16x32_f16(a, b, acc, 0, 0, 0)

__device__ __forceinline__ float fast_rcp(float x) { return __builtin_amdgcn_rcpf(x); }
__device__ __forceinline__ float sigf(float x)   { return fast_rcp(1.f + __expf(-x)); }
__device__ __forceinline__ float tanhf_(float x) { return 1.f - 2.f * fast_rcp(1.f + __expf(2.f * x)); }

typedef __attribute__((address_space(3))) unsigned lds_u32_t;
typedef const __attribute__((address_space(1))) unsigned glb_u32_t;
__device__ __forceinline__ void gl_lds16(const void* g, void* l) {
  __builtin_amdgcn_global_load_lds((glb_u32_t*)g, (lds_u32_t*)l, 16, 0, 0);
}

__device__ __forceinline__ f16x8 zf() {
  f16x8 r;
  #pragma unroll
  for (int i = 0; i < 8; ++i) r[i] = (_Float16)0.f;
  return r;
}
__device__ __forceinline__ f16x8 cvthi8(float4 a, float4 b) {
  f16x8 r;
  r[0] = (_Float16)a.x; r[1] = (_Float16)a.y; r[2] = (_Float16)a.z; r[3] = (_Float16)a.w;
  r[4] = (_Float16)b.x; r[5] = (_Float16)b.y; r[6] = (_Float16)b.z; r[7] = (_Float16)b.w;
  return r;
}
__device__ __forceinline__ f16x8 cvt8(const float* p) {
  return cvthi8(*(const float4*)p, *(const float4*)(p + 4));
}

__global__ __launch_bounds__(NTH, 2) void lstm2_wide_kernel(
    const float* __restrict__ x,
    const float* __restrict__ Wih0, const float* __restrict__ Whh0,
    const float* __restrict__ bih0, const float* __restrict__ bhh0,
    const float* __restrict__ Wih1, const float* __restrict__ Whh1,
    const float* __restrict__ bih1, const float* __restrict__ bhh1,
    const float* __restrict__ W1, const float* __restrict__ b1,
    const float* __restrict__ W2, const float* __restrict__ b2,
    float* __restrict__ out)
{
  // planes: 0,1 = h1 ping-pong (hi f16); 2,3 = h2 ping-pong (hi f16)
  __shared__ __align__(16) unsigned short s_h[4][RB * HS];  // 36864 B
  __shared__ __align__(16) float s_x[2][RB * XP];           // 22528 B (also final h2 f32)
  __shared__ __align__(16) float s_fc[2112];                //  8448 B: W1|b1|W2

  const int tid = threadIdx.x;
  const int l   = tid & 63;
  const int wv  = tid >> 6;        // j-quarter 0..3
  const int l15 = l & 15;
  const int lg  = l >> 4;
  const int jj  = wv * 16 + l15;
  const int k0l = lg * 8;
  const int blk = blockIdx.x;
  const float* xg = x + (size_t)blk * RB * (TT * DD);

  // ---- x-staging precompute: 704 chunks of 16B (64 rows x 11, last chunk is pad) ----
  const int c0 = tid, c1 = 256 + tid, c2 = 512 + tid;
  const int r0 = c0 / 11, p0 = c0 - r0 * 11;
  const int r1 = c1 / 11, p1 = c1 - r1 * 11;
  const int r2 = c2 / 11, p2 = c2 - r2 * 11;
  const bool v0 = (p0 < 10), v1 = (p1 < 10), v2 = (c2 < 704) && (p2 < 10);
  const float* xs0 = xg + r0 * (TT * DD) + p0 * 4;
  const float* xs1 = xg + r1 * (TT * DD) + p1 * 4;
  const float* xs2 = xg + r2 * (TT * DD) + p2 * 4;
  const int d0 = (wv * 64) * 4, d1 = (256 + wv * 64) * 4, d2 = (512 + wv * 64) * 4;

  // ---- prologue staging: x[0] and FC weights ----
  if (v0) gl_lds16(xs0, &s_x[0][d0]);
  if (v1) gl_lds16(xs1, &s_x[0][d1]);
  if (v2) gl_lds16(xs2, &s_x[0][d2]);
  gl_lds16(W1 + c0 * 4, &s_fc[d0]);           // W1 chunks 0..255
  gl_lds16(W1 + c1 * 4, &s_fc[d1]);           // W1 chunks 256..511
  if (tid < 16) {                              // b1 (8 chunks) | W2 (8 chunks)
    const float* src = (tid < 8) ? (b1 + tid * 4) : (W2 + (tid - 8) * 4);
    gl_lds16(src, &s_fc[2048]);
  }

  // ---- weight fragments in VGPRs (f16) ----
  f16x8 Bh0[4][2], Bh1[4][2], Bx1[4][2], Bx0k0[4], Bx0m[4];
  float bias1v[4];
  #pragma unroll
  for (int g = 0; g < 4; ++g) {
    int n = g * 64 + jj;
    #pragma unroll
    for (int kt = 0; kt < 2; ++kt) {
      Bh0[g][kt] = cvt8(&Whh0[n * HH + kt * 32 + k0l]);
      Bh1[g][kt] = cvt8(&Whh1[n * HH + kt * 32 + k0l]);
      Bx1[g][kt] = cvt8(&Wih1[n * HH + kt * 32 + k0l]);
    }
    Bx0k0[g] = cvt8(&Wih0[n * DD + k0l]);
    // merged tile: lg0 = Wih0[n][32..39]; lg2 slot0 = bias0 (A carries 1.0)
    f16x8 f = zf();
    if (lg == 0)      f = cvt8(&Wih0[n * DD + 32]);
    else if (lg == 2) f[0] = (_Float16)(bih0[n] + bhh0[n]);
    Bx0m[g] = f;
    bias1v[g] = bih1[n] + bhh1[n];
  }

  float cst0[NRT][4], cst1[NRT][4];
  #pragma unroll
  for (int rt = 0; rt < NRT; ++rt)
    #pragma unroll
    for (int r = 0; r < 4; ++r) { cst0[rt][r] = 0.f; cst1[rt][r] = 0.f; }

  __syncthreads();   // x[0] + FC staged (compiler drains vmcnt before barrier)

  #pragma unroll 1
  for (int s = 0; s < TT; ++s) {
    if (s) __syncthreads();
    if (s < TT - 1) {     // stage x[s+1] into the other buffer; consumed next interval
      float* xd = &s_x[(s + 1) & 1][0];
      const int so = (s + 1) * DD;
      if (v0) gl_lds16(xs0 + so, xd + d0);
      if (v1) gl_lds16(xs1 + so, xd + d1);
      if (v2) gl_lds16(xs2 + so, xd + d2);
    }
    const float* xb = &s_x[s & 1][0];
    const int p1r = (s - 1) & 1;

    #pragma unroll
    for (int rt = 0; rt < NRT; ++rt) {
      const int arow = rt * 16 + l15;
      const float* xr = xb + arow * XP;
      f16x8 xh0 = cvthi8(*(const float4*)(xr + k0l), *(const float4*)(xr + k0l + 4));
      f16x8 am1;
      if (lg == 0) am1 = cvthi8(*(const float4*)(xr + 32), *(const float4*)(xr + 36));
      else { am1 = zf(); if (lg == 2) am1[0] = (_Float16)1.f; }

      f32x4 a0[4];
      #pragma unroll
      for (int g = 0; g < 4; ++g) a0[g] = (f32x4){0.f, 0.f, 0.f, 0.f};
      f16x8 h1a, h1b;

      __builtin_amdgcn_s_setprio(1);
      #pragma unroll
      for (int g = 0; g < 4; ++g) MFMA(a0[g], xh0, Bx0k0[g]);
      #pragma unroll
      for (int g = 0; g < 4; ++g) MFMA(a0[g], am1, Bx0m[g]);
      if (s) {
        const unsigned short* hp = &s_h[p1r][arow * HS + k0l];
        h1a = *(const f16x8*)hp;
        h1b = *(const f16x8*)(hp + 32);
        #pragma unroll
        for (int g = 0; g < 4; ++g) MFMA(a0[g], h1a, Bh0[g][0]);
        #pragma unroll
        for (int g = 0; g < 4; ++g) MFMA(a0[g], h1b, Bh0[g][1]);
      }
      __builtin_amdgcn_s_setprio(0);

      #pragma unroll
      for (int r = 0; r < 4; ++r) {
        float ig = sigf(a0[0][r]);
        float fg = sigf(a0[1][r]);
        float gg = tanhf_(a0[2][r]);
        float og = sigf(a0[3][r]);
        float c  = fg * cst0[rt][r] + ig * gg;
        cst0[rt][r] = c;
        float h  = og * tanhf_(c);
        s_h[s & 1][(rt * 16 + lg * 4 + r) * HS + jj] =
            __builtin_bit_cast(unsigned short, (_Float16)h);
      }

      if (s) {   // L1: compute h2[s-1]
        f32x4 a1[4];
        #pragma unroll
        for (int g = 0; g < 4; ++g)
          a1[g] = (f32x4){bias1v[g], bias1v[g], bias1v[g], bias1v[g]};
        __builtin_amdgcn_s_setprio(1);
        #pragma unroll
        for (int g = 0; g < 4; ++g) MFMA(a1[g], h1a, Bx1[g][0]);
        #pragma unroll
        for (int g = 0; g < 4; ++g) MFMA(a1[g], h1b, Bx1[g][1]);
        if (s >= 2) {
          const unsigned short* qp = &s_h[2 + (s & 1)][arow * HS + k0l];
          f16x8 q0 = *(const f16x8*)qp;
          f16x8 q1 = *(const f16x8*)(qp + 32);
          #pragma unroll
          for (int g = 0; g < 4; ++g) MFMA(a1[g], q0, Bh1[g][0]);
          #pragma unroll
          for (int g = 0; g < 4; ++g) MFMA(a1[g], q1, Bh1[g][1]);
        }
        __builtin_amdgcn_s_setprio(0);
        #pragma unroll
        for (int r = 0; r < 4; ++r) {
          float ig = sigf(a1[0][r]);
          float fg = sigf(a1[1][r]);
          float gg = tanhf_(a1[2][r]);
          float og = sigf(a1[3][r]);
          float c  = fg * cst1[rt][r] + ig * gg;
          cst1[rt][r] = c;
          float h  = og * tanhf_(c);
          s_h[2 + p1r][(rt * 16 + lg * 4 + r) * HS + jj] =
              __builtin_bit_cast(unsigned short, (_Float16)h);
        }
      }
    }
  }

  // ---- final interval: h2[6] ----
  __syncthreads();
  {
    float* h2f = &s_x[0][0];   // [64][68] f32, overlays dead x buffers
    #pragma unroll
    for (int rt = 0; rt < NRT; ++rt) {
      const int arow = rt * 16 + l15;
      const unsigned short* hp = &s_h[0][arow * HS + k0l];   // h1[6]
      f16x8 h1a = *(const f16x8*)hp;
      f16x8 h1b = *(const f16x8*)(hp + 32);
      const unsigned short* qp = &s_h[3][arow * HS + k0l];   // h2[5]
      f16x8 q0 = *(const f16x8*)qp;
      f16x8 q1 = *(const f16x8*)(qp + 32);
      f32x4 a1[4];
      #pragma unroll
      for (int g = 0; g < 4; ++g)
        a1[g] = (f32x4){bias1v[g], bias1v[g], bias1v[g], bias1v[g]};
      __builtin_amdgcn_s_setprio(1);
      #pragma unroll
      for (int g = 0; g < 4; ++g) MFMA(a1[g], h1a, Bx1[g][0]);
      #pragma unroll
      for (int g = 0; g < 4; ++g) MFMA(a1[g], h1b, Bx1[g][1]);
      #pragma unroll
      for (int g = 0; g < 4; ++g) MFMA(a1[g], q0, Bh1[g][0]);
      #pragma unroll
      for (int g = 0; g < 4; ++g) MFMA(a1[g], q1, Bh1[g][1]);
      __builtin_amdgcn_s_setprio(0);
      #pragma unroll
      for (int r = 0; r < 4; ++r) {
        float ig = sigf(a1[0][r]);
        float fg = sigf(a1[1][r]);
        float gg = tanhf_(a1[2][r]);
        float og = sigf(a1[3][r]);
        float c  = fg * cst1[rt][r] + ig * gg;
        float h  = og * tanhf_(c);
        h2f[(rt * 16 + lg * 4 + r) * 68 + jj] = h;
      }
    }
  }
  __syncthreads();

  // ---- FC head (all operands in LDS) ----
  {
    const float* h2f = &s_x[0][0];
    float* hid = (float*)&s_h[0][0];   // [64][36] f32
    #pragma unroll 1
    for (int i = 0; i < 8; ++i) {
      int p = i * 256 + tid;
      int row = p >> 5, fc = p & 31;
      int rot = ((fc & 7) * 8 + (fc >> 3) * 4) & 63;   // bank de-rotation
      float a = s_fc[2048 + fc];
      #pragma unroll
      for (int kq = 0; kq < 16; ++kq) {
        int k = (rot + kq * 4) & 63;
        float4 hv = *(const float4*)&h2f[row * 68 + k];
        float4 wv = *(const float4*)&s_fc[fc * 64 + k];
        a += hv.x * wv.x + hv.y * wv.y + hv.z * wv.z + hv.w * wv.w;
      }
      hid[row * 36 + fc] = fmaxf(a, 0.f);
    }
  }
  __syncthreads();
  if (tid < RB) {
    const float* hid = (const float*)&s_h[0][0];
    float a = b2[0];
    #pragma unroll
    for (int k = 0; k < 32; ++k) a += hid[tid * 36 + k] * s_fc[2080 + k];
    out[blk * RB + tid] = a;
  }
}

extern "C" void kernel_launch(void* const* d_in, const int* in_sizes, int n_in,
                              void* d_out, int out_size, void* d_ws, size_t ws_size,
                              hipStream_t stream) {
  const float* x    = (const float*)d_in[0];
  const float* Wih0 = (const float*)d_in[1];
  const float* Whh0 = (const float*)d_in[2];
  const float* bih0 = (const float*)d_in[3];
  const float* bhh0 = (const float*)d_in[4];
  const float* Wih1 = (const float*)d_in[5];
  const float* Whh1 = (const float*)d_in[6];
  const float* bih1 = (const float*)d_in[7];
  const float* bhh1 = (const float*)d_in[8];
  const float* W1   = (const float*)d_in[9];
  const float* b1   = (const float*)d_in[10];
  const float* W2   = (const float*)d_in[11];
  const float* b2   = (const float*)d_in[12];
  float* out = (float*)d_out;

  const int Btot = in_sizes[0] / (TT * DD);   // 32768
  dim3 grid(Btot / RB), block(NTH);           // 512 blocks = 2 per CU exactly
  lstm2_wide_kernel<<<grid, block, 0, stream>>>(
      x, Wih0, Whh0, bih0, bhh0, Wih1, Whh1, bih1, bhh1, W1, b1, W2, b2, out);
}

// Round 8
// 70.579 us; speedup vs baseline: 4.2007x; 1.0863x over previous
//
#include <hip/hip_runtime.h>

#define TT 7
#define DD 40
#define HH 64
#define RB 128         // rows per block
#define NRT 4          // row-tiles of 16 per wave
#define NTH 512        // 8 waves = 2 row-halves x 4 j-quarters
#define HS 72          // u16 stride in h planes (144 B rows -> 2-way-free b128)
#define XP 44          // float stride of x rows in LDS (11 x 16B chunks)
#define L2E 1.44269504088896340736f

typedef _Float16 f16x8 __attribute__((ext_vector_type(8)));
typedef float f32x4 __attribute__((ext_vector_type(4)));

#define MFMA(acc, a, b) acc = __builtin_amdgcn_mfma_f32_16x16x32_f16(a, b, acc, 0, 0, 0)

__device__ __forceinline__ float fast_rcp(float x) { return __builtin_amdgcn_rcpf(x); }
// compiler-known TRANS op (hazard-safe, unlike raw inline asm): returns 2^x
__device__ __forceinline__ float ex2(float x) { return __builtin_amdgcn_exp2f(x); }

typedef __attribute__((address_space(3))) unsigned lds_u32_t;
typedef const __attribute__((address_space(1))) unsigned glb_u32_t;
__device__ __forceinline__ void gl_lds16(const void* g, void* l) {
  __builtin_amdgcn_global_load_lds((glb_u32_t*)g, (lds_u32_t*)l, 16, 0, 0);
}

__device__ __forceinline__ f16x8 zf() {
  f16x8 r;
  #pragma unroll
  for (int i = 0; i < 8; ++i) r[i] = (_Float16)0.f;
  return r;
}
__device__ __forceinline__ f16x8 cvt8s(const float* p, float s) {
  float4 a = *(const float4*)p, b = *(const float4*)(p + 4);
  f16x8 r;
  r[0] = (_Float16)(a.x * s); r[1] = (_Float16)(a.y * s);
  r[2] = (_Float16)(a.z * s); r[3] = (_Float16)(a.w * s);
  r[4] = (_Float16)(b.x * s); r[5] = (_Float16)(b.y * s);
  r[6] = (_Float16)(b.z * s); r[7] = (_Float16)(b.w * s);
  return r;
}
__device__ __forceinline__ f16x8 cvt8(const float* p) {
  float4 a = *(const float4*)p, b = *(const float4*)(p + 4);
  f16x8 r;
  r[0] = (_Float16)a.x; r[1] = (_Float16)a.y; r[2] = (_Float16)a.z; r[3] = (_Float16)a.w;
  r[4] = (_Float16)b.x; r[5] = (_Float16)b.y; r[6] = (_Float16)b.z; r[7] = (_Float16)b.w;
  return r;
}
// packed RTZ convert: 4 instrs for 8 values (x fragments only)
__device__ __forceinline__ f16x8 pk8(float4 a, float4 b) {
  f16x8 r;
  auto p0 = __builtin_amdgcn_cvt_pkrtz(a.x, a.y);
  auto p1 = __builtin_amdgcn_cvt_pkrtz(a.z, a.w);
  auto p2 = __builtin_amdgcn_cvt_pkrtz(b.x, b.y);
  auto p3 = __builtin_amdgcn_cvt_pkrtz(b.z, b.w);
  r[0] = p0[0]; r[1] = p0[1]; r[2] = p1[0]; r[3] = p1[1];
  r[4] = p2[0]; r[5] = p2[1]; r[6] = p3[0]; r[7] = p3[1];
  return r;
}

__global__ __launch_bounds__(NTH, 2) void lstm2_w512_kernel(
    const float* __restrict__ x,
    const float* __restrict__ Wih0, const float* __restrict__ Whh0,
    const float* __restrict__ bih0, const float* __restrict__ bhh0,
    const float* __restrict__ Wih1, const float* __restrict__ Whh1,
    const float* __restrict__ bih1, const float* __restrict__ bhh1,
    const float* __restrict__ W1, const float* __restrict__ b1,
    const float* __restrict__ W2, const float* __restrict__ b2,
    float* __restrict__ out)
{
  // planes: 0,1 = h1 ping-pong; 2,3 = h2 ping-pong (all f16). 127,232 B total.
  __shared__ __align__(16) unsigned short s_h[4][RB * HS];  // 73728 B
  __shared__ __align__(16) float s_x[2][RB * XP];           // 45056 B (tail: hid f32)
  __shared__ __align__(16) float s_fc[2112];                //  8448 B: W1|b1|W2

  const int tid = threadIdx.x;
  const int l   = tid & 63;
  const int wv  = tid >> 6;        // 0..7
  const int wm  = wv >> 2;         // row-half
  const int wn  = wv & 3;          // j-quarter
  const int l15 = l & 15;
  const int lg  = l >> 4;
  const int jj  = wn * 16 + l15;
  const int k0l = lg * 8;
  const int blk = blockIdx.x;
  const float* xg = x + (size_t)blk * RB * (TT * DD);

  // ---- x-staging: 1408 chunks of 16B (128 rows x 11; chunk 10 of each row = pad) ----
  const int c0 = tid, c1 = 512 + tid, c2 = 1024 + tid;
  const int r0 = c0 / 11, p0 = c0 - r0 * 11;
  const int r1 = c1 / 11, p1 = c1 - r1 * 11;
  const int r2 = c2 / 11, p2 = c2 - r2 * 11;
  const bool v0 = (p0 < 10), v1 = (p1 < 10), v2 = (c2 < 1408) && (p2 < 10);
  const float* xs0 = xg + r0 * (TT * DD) + p0 * 4;
  const float* xs1 = xg + r1 * (TT * DD) + p1 * 4;
  const float* xs2 = xg + r2 * (TT * DD) + p2 * 4;
  const int d0 = wv * 256, d1 = 2048 + wv * 256, d2 = 4096 + wv * 256; // float offs

  // ---- prologue staging: x[0] and FC weights ----
  if (v0) gl_lds16(xs0, &s_x[0][d0]);
  if (v1) gl_lds16(xs1, &s_x[0][d1]);
  if (v2) gl_lds16(xs2, &s_x[0][d2]);
  gl_lds16(W1 + tid * 4, &s_fc[wv * 256]);     // 512 chunks = all of W1
  if (tid < 16) {
    const float* src = (tid < 8) ? (b1 + tid * 4) : (W2 + (tid - 8) * 4);
    gl_lds16(src, &s_fc[2048]);
  }

  // ---- weight fragments in VGPRs (f16, log2e folded per gate) ----
  f16x8 Bh0[4][2], Bh1[4][2], Bx1[4][2], Bx0k0[4], Bx0k1[4];
  float bias0v[4], bias1v[4];
  #pragma unroll
  for (int g = 0; g < 4; ++g) {
    const float gs = (g == 2) ? 2.f * L2E : L2E;
    int n = g * 64 + jj;
    #pragma unroll
    for (int kt = 0; kt < 2; ++kt) {
      Bh0[g][kt] = cvt8s(&Whh0[n * HH + kt * 32 + k0l], gs);
      Bh1[g][kt] = cvt8s(&Whh1[n * HH + kt * 32 + k0l], gs);
      Bx1[g][kt] = cvt8s(&Wih1[n * HH + kt * 32 + k0l], gs);
    }
    Bx0k0[g] = cvt8s(&Wih0[n * DD + k0l], gs);
    Bx0k1[g] = (lg == 0) ? cvt8s(&Wih0[n * DD + 32], gs) : zf();  // k=32..39 tail
    bias0v[g] = (bih0[n] + bhh0[n]) * gs;
    bias1v[g] = (bih1[n] + bhh1[n]) * gs;
  }

  float cst0[NRT][4], cst1[NRT][4];
  #pragma unroll
  for (int rt = 0; rt < NRT; ++rt)
    #pragma unroll
    for (int r = 0; r < 4; ++r) { cst0[rt][r] = 0.f; cst1[rt][r] = 0.f; }

  __syncthreads();   // x[0] + FC staged (vmcnt drained at barrier)

  #pragma unroll 1
  for (int s = 0; s < TT; ++s) {
    if (s) __syncthreads();
    if (s < TT - 1) {          // stage x[s+1] into the other buffer
      float* xd = &s_x[(s + 1) & 1][0];
      const int so = (s + 1) * DD;
      if (v0) gl_lds16(xs0 + so, xd + d0);
      if (v1) gl_lds16(xs1 + so, xd + d1);
      if (v2) gl_lds16(xs2 + so, xd + d2);
    }
    const float* xb = &s_x[s & 1][0];
    const int p1r = (s - 1) & 1;

    #pragma unroll
    for (int rt = 0; rt < NRT; ++rt) {
      const int arow = wm * 64 + rt * 16 + l15;
      const float* xr = xb + arow * XP;
      f16x8 xh0 = pk8(*(const float4*)(xr + k0l), *(const float4*)(xr + k0l + 4));
      f16x8 am = xh0;
      if (lg == 0) am = pk8(*(const float4*)(xr + 32), *(const float4*)(xr + 36));

      f32x4 a0[4];
      #pragma unroll
      for (int g = 0; g < 4; ++g)
        a0[g] = (f32x4){bias0v[g], bias0v[g], bias0v[g], bias0v[g]};
      f16x8 h1a, h1b;

      __builtin_amdgcn_s_setprio(1);
      #pragma unroll
      for (int g = 0; g < 4; ++g) MFMA(a0[g], xh0, Bx0k0[g]);
      #pragma unroll
      for (int g = 0; g < 4; ++g) MFMA(a0[g], am, Bx0k1[g]);
      if (s) {
        const unsigned short* hp = &s_h[p1r][arow * HS + k0l];
        h1a = *(const f16x8*)hp;
        h1b = *(const f16x8*)(hp + 32);
        #pragma unroll
        for (int g = 0; g < 4; ++g) MFMA(a0[g], h1a, Bh0[g][0]);
        #pragma unroll
        for (int g = 0; g < 4; ++g) MFMA(a0[g], h1b, Bh0[g][1]);
      }
      __builtin_amdgcn_s_setprio(0);

      #pragma unroll
      for (int r = 0; r < 4; ++r) {
        float ig = fast_rcp(1.f + ex2(-a0[0][r]));
        float fg = fast_rcp(1.f + ex2(-a0[1][r]));
        float gg = 1.f - 2.f * fast_rcp(1.f + ex2(a0[2][r]));
        float og = fast_rcp(1.f + ex2(-a0[3][r]));
        float c  = fg * cst0[rt][r] + ig * gg;
        cst0[rt][r] = c;
        float h  = og * (1.f - 2.f * fast_rcp(1.f + ex2(c * (2.f * L2E))));
        s_h[s & 1][(wm * 64 + rt * 16 + lg * 4 + r) * HS + jj] =
            __builtin_bit_cast(unsigned short, (_Float16)h);
      }

      if (s) {   // L1: h2[s-1]
        f32x4 a1[4];
        #pragma unroll
        for (int g = 0; g < 4; ++g)
          a1[g] = (f32x4){bias1v[g], bias1v[g], bias1v[g], bias1v[g]};
        __builtin_amdgcn_s_setprio(1);
        #pragma unroll
        for (int g = 0; g < 4; ++g) MFMA(a1[g], h1a, Bx1[g][0]);
        #pragma unroll
        for (int g = 0; g < 4; ++g) MFMA(a1[g], h1b, Bx1[g][1]);
        if (s >= 2) {
          const unsigned short* qp = &s_h[2 + (s & 1)][arow * HS + k0l];
          f16x8 q0 = *(const f16x8*)qp;
          f16x8 q1 = *(const f16x8*)(qp + 32);
          #pragma unroll
          for (int g = 0; g < 4; ++g) MFMA(a1[g], q0, Bh1[g][0]);
          #pragma unroll
          for (int g = 0; g < 4; ++g) MFMA(a1[g], q1, Bh1[g][1]);
        }
        __builtin_amdgcn_s_setprio(0);
        #pragma unroll
        for (int r = 0; r < 4; ++r) {
          float ig = fast_rcp(1.f + ex2(-a1[0][r]));
          float fg = fast_rcp(1.f + ex2(-a1[1][r]));
          float gg = 1.f - 2.f * fast_rcp(1.f + ex2(a1[2][r]));
          float og = fast_rcp(1.f + ex2(-a1[3][r]));
          float c  = fg * cst1[rt][r] + ig * gg;
          cst1[rt][r] = c;
          float h  = og * (1.f - 2.f * fast_rcp(1.f + ex2(c * (2.f * L2E))));
          s_h[2 + p1r][(wm * 64 + rt * 16 + lg * 4 + r) * HS + jj] =
              __builtin_bit_cast(unsigned short, (_Float16)h);
        }
      }
    }
  }

  // ---- final interval: h2[6] -> f16 plane 1 ----
  __syncthreads();
  #pragma unroll
  for (int rt = 0; rt < NRT; ++rt) {
    const int arow = wm * 64 + rt * 16 + l15;
    const unsigned short* hp = &s_h[0][arow * HS + k0l];   // h1[6]
    f16x8 h1a = *(const f16x8*)hp;
    f16x8 h1b = *(const f16x8*)(hp + 32);
    const unsigned short* qp = &s_h[3][arow * HS + k0l];   // h2[5]
    f16x8 q0 = *(const f16x8*)qp;
    f16x8 q1 = *(const f16x8*)(qp + 32);
    f32x4 a1[4];
    #pragma unroll
    for (int g = 0; g < 4; ++g)
      a1[g] = (f32x4){bias1v[g], bias1v[g], bias1v[g], bias1v[g]};
    __builtin_amdgcn_s_setprio(1);
    #pragma unroll
    for (int g = 0; g < 4; ++g) MFMA(a1[g], h1a, Bx1[g][0]);
    #pragma unroll
    for (int g = 0; g < 4; ++g) MFMA(a1[g], h1b, Bx1[g][1]);
    #pragma unroll
    for (int g = 0; g < 4; ++g) MFMA(a1[g], q0, Bh1[g][0]);
    #pragma unroll
    for (int g = 0; g < 4; ++g) MFMA(a1[g], q1, Bh1[g][1]);
    __builtin_amdgcn_s_setprio(0);
    #pragma unroll
    for (int r = 0; r < 4; ++r) {
      float ig = fast_rcp(1.f + ex2(-a1[0][r]));
      float fg = fast_rcp(1.f + ex2(-a1[1][r]));
      float gg = 1.f - 2.f * fast_rcp(1.f + ex2(a1[2][r]));
      float og = fast_rcp(1.f + ex2(-a1[3][r]));
      float c  = fg * cst1[rt][r] + ig * gg;
      float h  = og * (1.f - 2.f * fast_rcp(1.f + ex2(c * (2.f * L2E))));
      s_h[1][(wm * 64 + rt * 16 + lg * 4 + r) * HS + jj] =
          __builtin_bit_cast(unsigned short, (_Float16)h);
    }
  }
  __syncthreads();

  // ---- FC head via MFMA: hid = relu(h2 @ W1^T + b1); wave wv owns row-tile wv ----
  {
    const unsigned short* ap = &s_h[1][(wv * 16 + l15) * HS + k0l];
    f16x8 A0 = *(const f16x8*)ap;
    f16x8 A1 = *(const f16x8*)(ap + 32);
    f16x8 Bf0[2], Bf1[2];
    f32x4 accf[2];
    #pragma unroll
    for (int f = 0; f < 2; ++f) {
      int n = f * 16 + l15;
      Bf0[f] = cvt8(&s_fc[n * 64 + k0l]);
      Bf1[f] = cvt8(&s_fc[n * 64 + 32 + k0l]);
      float bb = s_fc[2048 + n];
      accf[f] = (f32x4){bb, bb, bb, bb};
    }
    #pragma unroll
    for (int f = 0; f < 2; ++f) { MFMA(accf[f], A0, Bf0[f]); MFMA(accf[f], A1, Bf1[f]); }
    float* hid = &s_x[0][0];   // [128][36] f32
    #pragma unroll
    for (int f = 0; f < 2; ++f)
      #pragma unroll
      for (int r = 0; r < 4; ++r)
        hid[(wv * 16 + lg * 4 + r) * 36 + f * 16 + l15] = fmaxf(accf[f][r], 0.f);
  }
  __syncthreads();
  if (tid < RB) {
    const float* hid = &s_x[0][0];
    float a = b2[0];
    #pragma unroll
    for (int kq = 0; kq < 8; ++kq) {
      float4 hv = *(const float4*)&hid[tid * 36 + kq * 4];
      float4 wv4 = *(const float4*)&s_fc[2080 + kq * 4];
      a += hv.x * wv4.x + hv.y * wv4.y + hv.z * wv4.z + hv.w * wv4.w;
    }
    out[blk * RB + tid] = a;
  }
}

extern "C" void kernel_launch(void* const* d_in, const int* in_sizes, int n_in,
                              void* d_out, int out_size, void* d_ws, size_t ws_size,
                              hipStream_t stream) {
  const float* x    = (const float*)d_in[0];
  const float* Wih0 = (const float*)d_in[1];
  const float* Whh0 = (const float*)d_in[2];
  const float* bih0 = (const float*)d_in[3];
  const float* bhh0 = (const float*)d_in[4];
  const float* Wih1 = (const float*)d_in[5];
  const float* Whh1 = (const float*)d_in[6];
  const float* bih1 = (const float*)d_in[7];
  const float* bhh1 = (const float*)d_in[8];
  const float* W1   = (const float*)d_in[9];
  const float* b1   = (const float*)d_in[10];
  const float* W2   = (const float*)d_in[11];
  const float* b2   = (const float*)d_in[12];
  float* out = (float*)d_out;

  const int Btot = in_sizes[0] / (TT * DD);   // 32768
  dim3 grid(Btot / RB), block(NTH);           // 256 blocks = exactly 1 per CU
  lstm2_w512_kernel<<<grid, block, 0, stream>>>(
      x, Wih0, Whh0, bih0, bhh0, Wih1, Whh1, bih1, bhh1, W1, b1, W2, b2, out);
}